// Round 1
// baseline (214.255 us; speedup 1.0000x reference)
//
#include <hip/hip_runtime.h>

// CARAFE: N=8, C=256, H=W=64, UP=2, K=3 -> out (8,256,128,128) fp32
// Stage 1 (encoder): per (n,h) row block computes softmax weights (N,36,H,W) into d_ws.
// Stage 2 (reassemble): per-pixel 9-tap x 4-subpixel weighted sum + pixelshuffle.

#define EPS_BN 1e-5f

__global__ __launch_bounds__(256) void carafe_encoder(
    const float* __restrict__ x,
    const float* __restrict__ w0, const float* __restrict__ b0,
    const float* __restrict__ g0, const float* __restrict__ be0,
    const float* __restrict__ m0, const float* __restrict__ v0,
    const float* __restrict__ w1, const float* __restrict__ b1,
    const float* __restrict__ g1, const float* __restrict__ be1,
    const float* __restrict__ m1, const float* __restrict__ v1,
    float* __restrict__ wts)
{
    // LDS: xs = 128x64 x-chunk (32 KB), reused as y[64][64] (16 KB) later.
    //      wl = w0^T chunk [128][68] padded (34 KB), reused as w1^T [64*36] later.
    __shared__ float xs[128 * 64];
    __shared__ float wl[128 * 68];

    const int tid = threadIdx.x;
    const int b   = blockIdx.x;
    const int n   = b >> 6;      // 0..7
    const int hh  = b & 63;      // row
    const int w   = tid & 63;    // pixel col
    const int og  = tid >> 6;    // 0..3 (wave id; also softmax group u)

    float acc[16];
#pragma unroll
    for (int j = 0; j < 16; ++j) acc[j] = 0.f;

    // ---- layer0: y[o][w] = relu(bn0(w0 @ x + b0)), o = og*16+j ----
    for (int chunk = 0; chunk < 2; ++chunk) {
        const int c0 = chunk * 128;
        // stage x chunk: xs[cc][ww] = x[n][c0+cc][hh][ww]  (coalesced rows)
        for (int idx = tid; idx < 128 * 64; idx += 256) {
            const int cc = idx >> 6, ww = idx & 63;
            xs[idx] = x[((n * 256 + c0 + cc) * 64 + hh) * 64 + ww];
        }
        // stage w0 transposed: wl[cc*68 + o] = w0[o][c0+cc]  (coalesced in cc)
        for (int idx = tid; idx < 64 * 128; idx += 256) {
            const int o = idx >> 7, cc = idx & 127;
            wl[cc * 68 + o] = w0[o * 256 + c0 + cc];
        }
        __syncthreads();
#pragma unroll 4
        for (int cc = 0; cc < 128; ++cc) {
            const float xv = xs[cc * 64 + w];
            const float* wrow = &wl[cc * 68 + og * 16];
#pragma unroll
            for (int j = 0; j < 16; ++j)
                acc[j] = fmaf(xv, wrow[j], acc[j]);
        }
        __syncthreads();
    }

    // BN0 + ReLU; write y into xs region (x data dead now)
#pragma unroll
    for (int j = 0; j < 16; ++j) {
        const int o = og * 16 + j;
        const float sc = g0[o] * rsqrtf(v0[o] + EPS_BN);
        const float sh = (b0[o] - m0[o]) * sc + be0[o];
        xs[o * 64 + w] = fmaxf(fmaf(acc[j], sc, sh), 0.f);
    }
    // stage w1 transposed: wl[o*36 + p] = w1[p][o]
    for (int idx = tid; idx < 64 * 36; idx += 256) {
        const int o = idx / 36;
        const int p = idx - o * 36;
        wl[idx] = w1[p * 64 + o];
    }
    __syncthreads();

    // ---- layer1: enc[p][w], p = kk*4 + u, u = og. Each thread: all 9 kk for its u. ----
    float acc9[9];
#pragma unroll
    for (int kk = 0; kk < 9; ++kk) acc9[kk] = 0.f;
    const int u = og;
    for (int o = 0; o < 64; ++o) {
        const float yv = xs[o * 64 + w];
        const float* wrow = &wl[o * 36 + u];
#pragma unroll
        for (int kk = 0; kk < 9; ++kk)
            acc9[kk] = fmaf(yv, wrow[kk * 4], acc9[kk]);
    }

    // BN1 + ReLU, then softmax over kk
    float mx = -1e30f;
#pragma unroll
    for (int kk = 0; kk < 9; ++kk) {
        const int p = kk * 4 + u;
        const float sc = g1[p] * rsqrtf(v1[p] + EPS_BN);
        const float sh = (b1[p] - m1[p]) * sc + be1[p];
        float e = fmaxf(fmaf(acc9[kk], sc, sh), 0.f);
        acc9[kk] = e;
        mx = fmaxf(mx, e);
    }
    float s = 0.f;
#pragma unroll
    for (int kk = 0; kk < 9; ++kk) {
        acc9[kk] = __expf(acc9[kk] - mx);
        s += acc9[kk];
    }
    const float inv = 1.f / s;
#pragma unroll
    for (int kk = 0; kk < 9; ++kk)
        wts[((n * 36 + kk * 4 + u) * 64 + hh) * 64 + w] = acc9[kk] * inv;
}

// Stage 2: thread <-> (n, cg, h, w); 4 channels per thread.
__global__ __launch_bounds__(256) void carafe_reassemble(
    const float* __restrict__ x,
    const float* __restrict__ wts,
    float* __restrict__ out)
{
    const int t  = blockIdx.x * 256 + threadIdx.x;
    const int w  = t & 63;
    const int h  = (t >> 6) & 63;
    const int cg = (t >> 12) & 63;
    const int n  = t >> 18;

    // load 36 weights (each plane stride H*W=4096, coalesced across lanes)
    float wt[36];
    const float* wp = wts + ((n * 36) * 64 + h) * 64 + w;
#pragma unroll
    for (int p = 0; p < 36; ++p) wt[p] = wp[p * 4096];

#pragma unroll
    for (int i = 0; i < 4; ++i) {
        const int c = cg * 4 + i;
        const float* xp = x + (n * 256 + c) * 4096;
        float a0 = 0.f, a1 = 0.f, a2 = 0.f, a3 = 0.f;  // u = 0..3
#pragma unroll
        for (int dh = -1; dh <= 1; ++dh) {
            const int hhp = h + dh;
            const bool hv = (hhp >= 0) & (hhp < 64);
#pragma unroll
            for (int dw = -1; dw <= 1; ++dw) {
                const int wwp = w + dw;
                const bool vv = hv & (wwp >= 0) & (wwp < 64);
                const float xv = vv ? xp[hhp * 64 + wwp] : 0.f;
                const int k = (dh + 1) * 3 + (dw + 1);
                a0 = fmaf(xv, wt[k * 4 + 0], a0);
                a1 = fmaf(xv, wt[k * 4 + 1], a1);
                a2 = fmaf(xv, wt[k * 4 + 2], a2);
                a3 = fmaf(xv, wt[k * 4 + 3], a3);
            }
        }
        float* op = out + ((n * 256 + c) * 128 + 2 * h) * 128 + 2 * w;
        float2 r0; r0.x = a0; r0.y = a1;
        float2 r1; r1.x = a2; r1.y = a3;
        *reinterpret_cast<float2*>(op)       = r0;   // row 2h   : (u=0,u=1)
        *reinterpret_cast<float2*>(op + 128) = r1;   // row 2h+1 : (u=2,u=3)
    }
}

extern "C" void kernel_launch(void* const* d_in, const int* in_sizes, int n_in,
                              void* d_out, int out_size, void* d_ws, size_t ws_size,
                              hipStream_t stream)
{
    const float* x   = (const float*)d_in[0];
    const float* w0  = (const float*)d_in[1];
    const float* b0  = (const float*)d_in[2];
    const float* g0  = (const float*)d_in[3];
    const float* be0 = (const float*)d_in[4];
    const float* m0  = (const float*)d_in[5];
    const float* v0  = (const float*)d_in[6];
    const float* w1  = (const float*)d_in[7];
    const float* b1  = (const float*)d_in[8];
    const float* g1  = (const float*)d_in[9];
    const float* be1 = (const float*)d_in[10];
    const float* m1  = (const float*)d_in[11];
    const float* v1  = (const float*)d_in[12];

    float* wts = (float*)d_ws;          // N*36*H*W = 4,718,592 B
    float* out = (float*)d_out;

    hipLaunchKernelGGL(carafe_encoder, dim3(512), dim3(256), 0, stream,
                       x, w0, b0, g0, be0, m0, v0, w1, b1, g1, be1, m1, v1, wts);
    // N*H*W*(C/4) threads = 2,097,152 -> 8192 blocks
    hipLaunchKernelGGL(carafe_reassemble, dim3(8192), dim3(256), 0, stream,
                       x, wts, out);
}